// Round 6
// baseline (343.628 us; speedup 1.0000x reference)
//
#include <hip/hip_runtime.h>
#include <hip/hip_bf16.h>

// Problem constants (setup_inputs: B=2, N=256, D=256, H=8, LEN=516)
#define NPAIR 131072   // B*N*N
#define NUNIT 8192     // NPAIR / 16 pairs per MFMA tile
#define NH    8        // heads
#define NN    256      // N (k-dimension for topk / ind)
#define NROWS 512      // B*N rows for topk
#define LEN   516      // 2*D + 4
#define EPSV  1e-8f

// v4 geometry: 512 blocks x 256 threads (4 waves); each wave owns 4 units.
#define BLOCKS   512
#define WAVES_PB 4
#define UPW      4             // units per wave = 8192/(512*4)
#define NQ       (UPW * 4)     // quarter-tiles per wave (unit = 4 quarters)

typedef __attribute__((ext_vector_type(8))) short bf16x8;  // MFMA A/B frag
typedef __attribute__((ext_vector_type(4))) float f32x4;   // MFMA C/D frag
typedef unsigned int u32;

__device__ __forceinline__ unsigned int pk2(float x, float y) {
    union { __hip_bfloat162 h; unsigned int u; } c;
    c.h = __float22bfloat162_rn(make_float2(x, y));
    return c.u;   // low 16 = x, high 16 = y
}
__device__ __forceinline__ bf16x8 pack8(float4 a, float4 b) {
    union { unsigned int u[4]; bf16x8 v; } r;
    r.u[0] = pk2(a.x, a.y);
    r.u[1] = pk2(a.z, a.w);
    r.u[2] = pk2(b.x, b.y);
    r.u[3] = pk2(b.z, b.w);
    return r.v;
}

// Async global->LDS, 16 B per lane, LDS dest = uniform base + lane*16.
__device__ __forceinline__ void gload16(const void* g, void* l) {
    __builtin_amdgcn_global_load_lds(
        (const __attribute__((address_space(1))) u32*)g,
        (__attribute__((address_space(3))) u32*)l, 16, 0, 0);
}

// v4: rounds 0-5 showed dur/BW INVARIANT (113 us, 1.23 TB/s) across W-LDS
// and register-pipeline changes -> HBM-bound on the ACCESS PATTERN:
// per-lane 16-B fragments at 1-KB row stride = 32 scattered line
// transactions per instruction; 136 MB HBM / 1.23 TB/s = 110 us = measured.
// Fix: stage Q/K quarter-tiles (16 rows x 256 B, rows CONTIGUOUS in HBM)
// into LDS via global_load_lds with sequential 1-KB bursts; fragments via
// ds_read_b128 from an XOR-swizzled layout (16B-unit ^ (row&7): 2-way
// bank aliasing only, free per m136). 2-deep pipeline with counted
// vmcnt(8) (never 0 mid-loop); slot-reuse race closed by lgkmcnt(0)
// before re-staging (global_load_lds dest is linear, so the SOURCE is
// pre-swizzled - both-sides-or-neither, rule 21). W fragments back in
// registers: occupancy is LDS-capped (64 KB/block, 2 blocks/CU) so VGPRs
// are free. Epilogue SQ/SK/ROI loads issued at unit START so compiler
// auto-waits on them don't drain the stage queue (FIFO vmcnt).
__global__ void fused_main(
    const float* __restrict__ Q, const float* __restrict__ K,
    const float* __restrict__ SQ, const float* __restrict__ SK,
    const float* __restrict__ ROI, const float* __restrict__ W,
    const float* __restrict__ Bb, float* __restrict__ out,
    float* __restrict__ scores, float* __restrict__ ind)
{
    // [wave][slot][ Q 4096 B | K 4096 B ]  = 64 KB total
    __shared__ __align__(16) unsigned char lds[WAVES_PB][2][8192];

    // Folded zero_ind (stream-ordered before topk launch).
    if (blockIdx.x == 0 && threadIdx.x < NN) ind[threadIdx.x] = 0.0f;

    const int tid  = threadIdx.x;
    const int wid  = tid >> 6;
    const int l    = tid & 63;
    const int quad = l >> 4;        // 0..3
    const int m    = l & 15;        // tile row (pairs) / tile col (heads)
    const int hh   = m & 7;         // W row for this lane's output column
    const int s7   = m & 7;         // read-side swizzle key

    // W fragments persistent in registers (64 VGPR; LDS caps occupancy).
    bf16x8 wqf[8], wkf[8];
#pragma unroll
    for (int c = 0; c < 8; ++c) {
        const float* wp = W + hh * LEN + c * 32 + quad * 8;
        wqf[c] = pack8(*(const float4*)wp,         *(const float4*)(wp + 4));
        wkf[c] = pack8(*(const float4*)(wp + 256), *(const float4*)(wp + 260));
    }
    const float4 wt = *(const float4*)(W + hh * LEN + 512);
    const float bh = Bb[hh];

    const bool diag_owner = ((m >> 2) == quad);   // owns diag element m
    const int  dreg = m & 3;

    const int gw = blockIdx.x * WAVES_PB + wid;   // global wave 0..2047
    const int u0 = gw * UPW;                      // first unit of this wave

    // staging lane roles: instr i covers rows 4i..4i+3; lane -> (row, unit)
    const int smm = l >> 4;        // row sub-index within group of 4
    const int slu = l & 15;        // 16-B unit within the 256-B row-quarter

    // Stage quarter t into slot[t&1]: 8x global_load_lds, sequential
    // 1-KB bursts. LDS unit (mm, lu) receives global unit lu^(mm&7)
    // (inverse-swizzled source; LDS dest strictly linear).
    auto STAGE = [&](int t) {
        const int un  = u0 + (t >> 2);
        const int qtr = t & 3;
        unsigned char* slot = &lds[wid][t & 1][0];
#pragma unroll
        for (int i = 0; i < 4; ++i) {
            const int mm = i * 4 + smm;
            const int fo = (slu ^ (mm & 7)) << 2;   // float offset in quarter
            const size_t rb = (size_t)(un * 16 + mm) * 256 + qtr * 64 + fo;
            gload16(Q + rb, slot + i * 1024);
            gload16(K + rb, slot + 4096 + i * 1024);
        }
    };

    f32x4 a_qk = {0.f, 0.f, 0.f, 0.f};
    f32x4 a_qq = {0.f, 0.f, 0.f, 0.f};
    f32x4 a_kk = {0.f, 0.f, 0.f, 0.f};
    f32x4 a_pr = {0.f, 0.f, 0.f, 0.f};

    float2 esq[4], esk[4];
    float  eroi[4];

    STAGE(0);
    STAGE(1);

#pragma unroll
    for (int t = 0; t < NQ; ++t) {
        // stage(t) complete; allow stage(t+1) (8 ops) to stay in flight.
        if (t == NQ - 1) { asm volatile("s_waitcnt vmcnt(0)" ::: "memory"); }
        else             { asm volatile("s_waitcnt vmcnt(8)" ::: "memory"); }
        __builtin_amdgcn_sched_barrier(0);

        // Unit-start: issue epilogue input loads EARLY (oldest in the
        // vmcnt FIFO, so their auto-waits never drain later stages).
        if ((t & 3) == 0 && m < NH) {
            const int p0 = (u0 + (t >> 2)) * 16;
#pragma unroll
            for (int r = 0; r < 4; ++r) {
                const int p = p0 + quad * 4 + r;
                esq[r]  = ((const float2*)SQ)[p];
                esk[r]  = ((const float2*)SK)[p];
                eroi[r] = ROI[p];
            }
        }

        // Fragment raw reads (ds_read_b128), swizzled addresses.
        unsigned char* slot = &lds[wid][t & 1][0];
        const int b   = m * 256;
        const int u00 = ((2 * quad + 0) ^ s7) << 4;
        const int u01 = ((2 * quad + 1) ^ s7) << 4;
        const int u10 = ((8 + 2 * quad + 0) ^ s7) << 4;
        const int u11 = ((8 + 2 * quad + 1) ^ s7) << 4;
        const float4 qr00 = *(const float4*)(slot + b + u00);
        const float4 qr01 = *(const float4*)(slot + b + u01);
        const float4 qr10 = *(const float4*)(slot + b + u10);
        const float4 qr11 = *(const float4*)(slot + b + u11);
        const float4 kr00 = *(const float4*)(slot + 4096 + b + u00);
        const float4 kr01 = *(const float4*)(slot + 4096 + b + u01);
        const float4 kr10 = *(const float4*)(slot + 4096 + b + u10);
        const float4 kr11 = *(const float4*)(slot + 4096 + b + u11);
        // Reads landed -> safe to overwrite this slot (stage t+2).
        asm volatile("s_waitcnt lgkmcnt(0)" ::: "memory");
        __builtin_amdgcn_sched_barrier(0);

        if (t + 2 < NQ) STAGE(t + 2);

        const int c0 = (t & 3) * 2;   // static after unroll (rule 20)
        {
            const bf16x8 qf = pack8(qr00, qr01);
            const bf16x8 kf = pack8(kr00, kr01);
            a_qk = __builtin_amdgcn_mfma_f32_16x16x32_bf16(qf, kf, a_qk, 0, 0, 0);
            a_qq = __builtin_amdgcn_mfma_f32_16x16x32_bf16(qf, qf, a_qq, 0, 0, 0);
            a_kk = __builtin_amdgcn_mfma_f32_16x16x32_bf16(kf, kf, a_kk, 0, 0, 0);
            a_pr = __builtin_amdgcn_mfma_f32_16x16x32_bf16(qf, wqf[c0], a_pr, 0, 0, 0);
            a_pr = __builtin_amdgcn_mfma_f32_16x16x32_bf16(kf, wkf[c0], a_pr, 0, 0, 0);
        }
        {
            const bf16x8 qf = pack8(qr10, qr11);
            const bf16x8 kf = pack8(kr10, kr11);
            a_qk = __builtin_amdgcn_mfma_f32_16x16x32_bf16(qf, kf, a_qk, 0, 0, 0);
            a_qq = __builtin_amdgcn_mfma_f32_16x16x32_bf16(qf, qf, a_qq, 0, 0, 0);
            a_kk = __builtin_amdgcn_mfma_f32_16x16x32_bf16(kf, kf, a_kk, 0, 0, 0);
            a_pr = __builtin_amdgcn_mfma_f32_16x16x32_bf16(qf, wqf[c0 + 1], a_pr, 0, 0, 0);
            a_pr = __builtin_amdgcn_mfma_f32_16x16x32_bf16(kf, wkf[c0 + 1], a_pr, 0, 0, 0);
        }

        if ((t & 3) == 3) {   // unit complete: epilogue
            const int p0 = (u0 + (t >> 2)) * 16;
            if (diag_owner) {
                const float qk = a_qk[dreg];
                const float qq = a_qq[dreg];
                const float kk = a_kk[dreg];
                const float d = fmaxf(sqrtf(qq), EPSV) * fmaxf(sqrtf(kk), EPSV);
                scores[p0 + m] = fmaxf(qk / d, 0.0f);
            }
            if (m < NH) {
#pragma unroll
                for (int r = 0; r < 4; ++r) {
                    const int p = p0 + quad * 4 + r;
                    const float x = a_pr[r] + esq[r].x * wt.x + esq[r].y * wt.y
                                            + esk[r].x * wt.z + esk[r].y * wt.w + bh;
                    out[(size_t)p * NH + m] = eroi[r] / (1.0f + __expf(-x));
                }
            }
            a_qk = {0.f, 0.f, 0.f, 0.f};
            a_qq = {0.f, 0.f, 0.f, 0.f};
            a_kk = {0.f, 0.f, 0.f, 0.f};
            a_pr = {0.f, 0.f, 0.f, 0.f};
        }
    }
}

// Kernel 2: per (b,q) row, extract top-k indices (stable: ties -> lower
// index) and mark ind[idx] = 1.0. One wave per row.
__global__ __launch_bounds__(64) void topk_kernel(
    const float* __restrict__ scores, float* __restrict__ ind,
    const int* __restrict__ node_num)
{
    const int row = blockIdx.x;
    const int lane = threadIdx.x;
    const float4 v4 = *(const float4*)(scores + row * NN + lane * 4);
    float v[4] = {v4.x, v4.y, v4.z, v4.w};

    int Kk = node_num[0];
    if (Kk > NN) Kk = NN;
    for (int t = 0; t < Kk; t++) {
        float mv = v[0];
        int mi = lane * 4;
#pragma unroll
        for (int j = 1; j < 4; j++) {
            if (v[j] > mv) { mv = v[j]; mi = lane * 4 + j; }
        }
        for (int off = 32; off > 0; off >>= 1) {
            const float ov = __shfl_xor(mv, off, 64);
            const int   oi = __shfl_xor(mi, off, 64);
            if (ov > mv || (ov == mv && oi < mi)) { mv = ov; mi = oi; }
        }
        if (lane == 0) ind[mi] = 1.0f;             // idempotent 1.0 store
        if ((mi >> 2) == lane) v[mi & 3] = -1.0f;  // remove (scores >= 0)
    }
}

// Kernel 3: out *= ind[k]; float4 over out (element e: k = (e/8)%256).
__global__ __launch_bounds__(256) void apply_ind_kernel(
    float* __restrict__ out, const float* __restrict__ ind)
{
    const int i = blockIdx.x * blockDim.x + threadIdx.x;  // float4 index
    float4 v = ((float4*)out)[i];
    const float m = ind[(i >> 1) & (NN - 1)];
    v.x *= m; v.y *= m; v.z *= m; v.w *= m;
    ((float4*)out)[i] = v;
}

extern "C" void kernel_launch(void* const* d_in, const int* in_sizes, int n_in,
                              void* d_out, int out_size, void* d_ws, size_t ws_size,
                              hipStream_t stream)
{
    const float* Q   = (const float*)d_in[0];
    const float* K   = (const float*)d_in[1];
    const float* SQ  = (const float*)d_in[2];
    const float* SK  = (const float*)d_in[3];
    const float* ROI = (const float*)d_in[4];
    const float* W   = (const float*)d_in[5];
    const float* Bb  = (const float*)d_in[6];
    const int* node_num = (const int*)d_in[7];

    float* out = (float*)d_out;
    float* scores = (float*)d_ws;          // NPAIR floats (512 KB)
    float* ind = scores + NPAIR;           // NN floats

    fused_main<<<BLOCKS, 256, 0, stream>>>(Q, K, SQ, SK, ROI, W, Bb, out,
                                           scores, ind);
    topk_kernel<<<NROWS, 64, 0, stream>>>(scores, ind, node_num);
    apply_ind_kernel<<<out_size / 4 / 256, 256, 0, stream>>>(out, ind);
}

// Round 7
// 325.108 us; speedup vs baseline: 1.0570x; 1.0570x over previous
//
#include <hip/hip_runtime.h>
#include <hip/hip_bf16.h>

// Problem constants (setup_inputs: B=2, N=256, D=256, H=8, LEN=516)
#define NPAIR 131072   // B*N*N
#define NUNIT 8192     // NPAIR / 16 pairs per MFMA tile
#define NH    8        // heads
#define NN    256      // N (k-dimension for topk / ind)
#define NROWS 512      // B*N rows for topk
#define LEN   516      // 2*D + 4
#define EPSV  1e-8f

// v4 geometry: 512 blocks x 256 threads (4 waves); each wave owns 4 units.
#define BLOCKS   512
#define WAVES_PB 4
#define UPW      4             // units per wave = 8192/(512*4)
#define NQ       (UPW * 4)     // quarter-tiles per wave (unit = 4 quarters)

typedef __attribute__((ext_vector_type(8))) short bf16x8;  // MFMA A/B frag
typedef __attribute__((ext_vector_type(4))) float f32x4;   // MFMA C/D frag
typedef unsigned int u32;

__device__ __forceinline__ unsigned int pk2(float x, float y) {
    union { __hip_bfloat162 h; unsigned int u; } c;
    c.h = __float22bfloat162_rn(make_float2(x, y));
    return c.u;   // low 16 = x, high 16 = y
}
__device__ __forceinline__ bf16x8 pack8(float4 a, float4 b) {
    union { unsigned int u[4]; bf16x8 v; } r;
    r.u[0] = pk2(a.x, a.y);
    r.u[1] = pk2(a.z, a.w);
    r.u[2] = pk2(b.x, b.y);
    r.u[3] = pk2(b.z, b.w);
    return r.v;
}

// Async global->LDS, 16 B per lane, LDS dest = uniform base + lane*16.
__device__ __forceinline__ void gload16(const void* g, void* l) {
    __builtin_amdgcn_global_load_lds(
        (const __attribute__((address_space(1))) u32*)g,
        (__attribute__((address_space(3))) u32*)l, 16, 0, 0);
}

// v4: staged Q/K quarter-tiles via global_load_lds (sequential 1-KB
// bursts) + XOR-swizzled ds_read_b128 + 2-deep counted-vmcnt pipeline.
// Measured: hbm_gbps 1231->2321 (+89%, pattern theory CONFIRMED) but
// dur 113->131 us because VGPR_Count stayed 64 -> ~650 B/thread scratch
// spill (WRITE_SIZE 4.6->85 MB, FETCH +70 MB re-reads). The asm
// waitcnt/sched_barrier structure blocked the AGPR parking that rounds
// 0-5 used for W frags; everything past 64 arch-VGPRs went to scratch.
// v5 (this round): __launch_bounds__(256, 1) — min 1 wave/EU raises the
// per-wave VGPR budget to the full file so the ~180-reg working set
// stays in registers. Occupancy is LDS-capped at 2 blocks/CU (8
// waves/CU); ~200 VGPRs still allows 2 waves/SIMD -> SAME occupancy,
// zero cost. Single-variable experiment vs v4.
__global__ __launch_bounds__(256, 1) void fused_main(
    const float* __restrict__ Q, const float* __restrict__ K,
    const float* __restrict__ SQ, const float* __restrict__ SK,
    const float* __restrict__ ROI, const float* __restrict__ W,
    const float* __restrict__ Bb, float* __restrict__ out,
    float* __restrict__ scores, float* __restrict__ ind)
{
    // [wave][slot][ Q 4096 B | K 4096 B ]  = 64 KB total
    __shared__ __align__(16) unsigned char lds[WAVES_PB][2][8192];

    // Folded zero_ind (stream-ordered before topk launch).
    if (blockIdx.x == 0 && threadIdx.x < NN) ind[threadIdx.x] = 0.0f;

    const int tid  = threadIdx.x;
    const int wid  = tid >> 6;
    const int l    = tid & 63;
    const int quad = l >> 4;        // 0..3
    const int m    = l & 15;        // tile row (pairs) / tile col (heads)
    const int hh   = m & 7;         // W row for this lane's output column
    const int s7   = m & 7;         // read-side swizzle key

    // W fragments persistent in registers (64 VGPR; LDS caps occupancy).
    bf16x8 wqf[8], wkf[8];
#pragma unroll
    for (int c = 0; c < 8; ++c) {
        const float* wp = W + hh * LEN + c * 32 + quad * 8;
        wqf[c] = pack8(*(const float4*)wp,         *(const float4*)(wp + 4));
        wkf[c] = pack8(*(const float4*)(wp + 256), *(const float4*)(wp + 260));
    }
    const float4 wt = *(const float4*)(W + hh * LEN + 512);
    const float bh = Bb[hh];

    const bool diag_owner = ((m >> 2) == quad);   // owns diag element m
    const int  dreg = m & 3;

    const int gw = blockIdx.x * WAVES_PB + wid;   // global wave 0..2047
    const int u0 = gw * UPW;                      // first unit of this wave

    // staging lane roles: instr i covers rows 4i..4i+3; lane -> (row, unit)
    const int smm = l >> 4;        // row sub-index within group of 4
    const int slu = l & 15;        // 16-B unit within the 256-B row-quarter

    // Stage quarter t into slot[t&1]: 8x global_load_lds, sequential
    // 1-KB bursts. LDS unit (mm, lu) receives global unit lu^(mm&7)
    // (inverse-swizzled source; LDS dest strictly linear).
    auto STAGE = [&](int t) {
        const int un  = u0 + (t >> 2);
        const int qtr = t & 3;
        unsigned char* slot = &lds[wid][t & 1][0];
#pragma unroll
        for (int i = 0; i < 4; ++i) {
            const int mm = i * 4 + smm;
            const int fo = (slu ^ (mm & 7)) << 2;   // float offset in quarter
            const size_t rb = (size_t)(un * 16 + mm) * 256 + qtr * 64 + fo;
            gload16(Q + rb, slot + i * 1024);
            gload16(K + rb, slot + 4096 + i * 1024);
        }
    };

    f32x4 a_qk = {0.f, 0.f, 0.f, 0.f};
    f32x4 a_qq = {0.f, 0.f, 0.f, 0.f};
    f32x4 a_kk = {0.f, 0.f, 0.f, 0.f};
    f32x4 a_pr = {0.f, 0.f, 0.f, 0.f};

    float2 esq[4], esk[4];
    float  eroi[4];

    STAGE(0);
    STAGE(1);

#pragma unroll
    for (int t = 0; t < NQ; ++t) {
        // stage(t) complete; allow stage(t+1) (8 ops) to stay in flight.
        if (t == NQ - 1) { asm volatile("s_waitcnt vmcnt(0)" ::: "memory"); }
        else             { asm volatile("s_waitcnt vmcnt(8)" ::: "memory"); }
        __builtin_amdgcn_sched_barrier(0);

        // Unit-start: issue epilogue input loads EARLY (oldest in the
        // vmcnt FIFO, so their auto-waits never drain later stages).
        if ((t & 3) == 0 && m < NH) {
            const int p0 = (u0 + (t >> 2)) * 16;
#pragma unroll
            for (int r = 0; r < 4; ++r) {
                const int p = p0 + quad * 4 + r;
                esq[r]  = ((const float2*)SQ)[p];
                esk[r]  = ((const float2*)SK)[p];
                eroi[r] = ROI[p];
            }
        }

        // Fragment raw reads (ds_read_b128), swizzled addresses.
        unsigned char* slot = &lds[wid][t & 1][0];
        const int b   = m * 256;
        const int u00 = ((2 * quad + 0) ^ s7) << 4;
        const int u01 = ((2 * quad + 1) ^ s7) << 4;
        const int u10 = ((8 + 2 * quad + 0) ^ s7) << 4;
        const int u11 = ((8 + 2 * quad + 1) ^ s7) << 4;
        const float4 qr00 = *(const float4*)(slot + b + u00);
        const float4 qr01 = *(const float4*)(slot + b + u01);
        const float4 qr10 = *(const float4*)(slot + b + u10);
        const float4 qr11 = *(const float4*)(slot + b + u11);
        const float4 kr00 = *(const float4*)(slot + 4096 + b + u00);
        const float4 kr01 = *(const float4*)(slot + 4096 + b + u01);
        const float4 kr10 = *(const float4*)(slot + 4096 + b + u10);
        const float4 kr11 = *(const float4*)(slot + 4096 + b + u11);
        // Reads landed -> safe to overwrite this slot (stage t+2).
        asm volatile("s_waitcnt lgkmcnt(0)" ::: "memory");
        __builtin_amdgcn_sched_barrier(0);

        if (t + 2 < NQ) STAGE(t + 2);

        const int c0 = (t & 3) * 2;   // static after unroll (rule 20)
        {
            const bf16x8 qf = pack8(qr00, qr01);
            const bf16x8 kf = pack8(kr00, kr01);
            a_qk = __builtin_amdgcn_mfma_f32_16x16x32_bf16(qf, kf, a_qk, 0, 0, 0);
            a_qq = __builtin_amdgcn_mfma_f32_16x16x32_bf16(qf, qf, a_qq, 0, 0, 0);
            a_kk = __builtin_amdgcn_mfma_f32_16x16x32_bf16(kf, kf, a_kk, 0, 0, 0);
            a_pr = __builtin_amdgcn_mfma_f32_16x16x32_bf16(qf, wqf[c0], a_pr, 0, 0, 0);
            a_pr = __builtin_amdgcn_mfma_f32_16x16x32_bf16(kf, wkf[c0], a_pr, 0, 0, 0);
        }
        {
            const bf16x8 qf = pack8(qr10, qr11);
            const bf16x8 kf = pack8(kr10, kr11);
            a_qk = __builtin_amdgcn_mfma_f32_16x16x32_bf16(qf, kf, a_qk, 0, 0, 0);
            a_qq = __builtin_amdgcn_mfma_f32_16x16x32_bf16(qf, qf, a_qq, 0, 0, 0);
            a_kk = __builtin_amdgcn_mfma_f32_16x16x32_bf16(kf, kf, a_kk, 0, 0, 0);
            a_pr = __builtin_amdgcn_mfma_f32_16x16x32_bf16(qf, wqf[c0 + 1], a_pr, 0, 0, 0);
            a_pr = __builtin_amdgcn_mfma_f32_16x16x32_bf16(kf, wkf[c0 + 1], a_pr, 0, 0, 0);
        }

        if ((t & 3) == 3) {   // unit complete: epilogue
            const int p0 = (u0 + (t >> 2)) * 16;
            if (diag_owner) {
                const float qk = a_qk[dreg];
                const float qq = a_qq[dreg];
                const float kk = a_kk[dreg];
                const float d = fmaxf(sqrtf(qq), EPSV) * fmaxf(sqrtf(kk), EPSV);
                scores[p0 + m] = fmaxf(qk / d, 0.0f);
            }
            if (m < NH) {
#pragma unroll
                for (int r = 0; r < 4; ++r) {
                    const int p = p0 + quad * 4 + r;
                    const float x = a_pr[r] + esq[r].x * wt.x + esq[r].y * wt.y
                                            + esk[r].x * wt.z + esk[r].y * wt.w + bh;
                    out[(size_t)p * NH + m] = eroi[r] / (1.0f + __expf(-x));
                }
            }
            a_qk = {0.f, 0.f, 0.f, 0.f};
            a_qq = {0.f, 0.f, 0.f, 0.f};
            a_kk = {0.f, 0.f, 0.f, 0.f};
            a_pr = {0.f, 0.f, 0.f, 0.f};
        }
    }
}

// Kernel 2: per (b,q) row, extract top-k indices (stable: ties -> lower
// index) and mark ind[idx] = 1.0. One wave per row.
__global__ __launch_bounds__(64) void topk_kernel(
    const float* __restrict__ scores, float* __restrict__ ind,
    const int* __restrict__ node_num)
{
    const int row = blockIdx.x;
    const int lane = threadIdx.x;
    const float4 v4 = *(const float4*)(scores + row * NN + lane * 4);
    float v[4] = {v4.x, v4.y, v4.z, v4.w};

    int Kk = node_num[0];
    if (Kk > NN) Kk = NN;
    for (int t = 0; t < Kk; t++) {
        float mv = v[0];
        int mi = lane * 4;
#pragma unroll
        for (int j = 1; j < 4; j++) {
            if (v[j] > mv) { mv = v[j]; mi = lane * 4 + j; }
        }
        for (int off = 32; off > 0; off >>= 1) {
            const float ov = __shfl_xor(mv, off, 64);
            const int   oi = __shfl_xor(mi, off, 64);
            if (ov > mv || (ov == mv && oi < mi)) { mv = ov; mi = oi; }
        }
        if (lane == 0) ind[mi] = 1.0f;             // idempotent 1.0 store
        if ((mi >> 2) == lane) v[mi & 3] = -1.0f;  // remove (scores >= 0)
    }
}

// Kernel 3: out *= ind[k]; float4 over out (element e: k = (e/8)%256).
__global__ __launch_bounds__(256) void apply_ind_kernel(
    float* __restrict__ out, const float* __restrict__ ind)
{
    const int i = blockIdx.x * blockDim.x + threadIdx.x;  // float4 index
    float4 v = ((float4*)out)[i];
    const float m = ind[(i >> 1) & (NN - 1)];
    v.x *= m; v.y *= m; v.z *= m; v.w *= m;
    ((float4*)out)[i] = v;
}

extern "C" void kernel_launch(void* const* d_in, const int* in_sizes, int n_in,
                              void* d_out, int out_size, void* d_ws, size_t ws_size,
                              hipStream_t stream)
{
    const float* Q   = (const float*)d_in[0];
    const float* K   = (const float*)d_in[1];
    const float* SQ  = (const float*)d_in[2];
    const float* SK  = (const float*)d_in[3];
    const float* ROI = (const float*)d_in[4];
    const float* W   = (const float*)d_in[5];
    const float* Bb  = (const float*)d_in[6];
    const int* node_num = (const int*)d_in[7];

    float* out = (float*)d_out;
    float* scores = (float*)d_ws;          // NPAIR floats (512 KB)
    float* ind = scores + NPAIR;           // NN floats

    fused_main<<<BLOCKS, 256, 0, stream>>>(Q, K, SQ, SK, ROI, W, Bb, out,
                                           scores, ind);
    topk_kernel<<<NROWS, 64, 0, stream>>>(scores, ind, node_num);
    apply_ind_kernel<<<out_size / 4 / 256, 256, 0, stream>>>(out, ind);
}